// Round 2
// baseline (25.680 us; speedup 1.0000x reference)
//
#include <hip/hip_runtime.h>

// L_x1 L_x2 of RBF kernel k(x1,x2)=exp(-||x1-x2||^2/(2 l^2)) in D=2.
// Closed form: with a = 1/l^2, s = ||x1-x2||^2, t = a*s:
//   L_x1 L_x2 k = exp(-t/2) * a^2 * (t^2 - 8 t + 8)
//               = exp(-0.5*a*s) * (a^4 s^2 - 8 a^3 s + 8 a^2)

#define N1 4096
#define N2 4096

typedef float v4f __attribute__((ext_vector_type(4)));

__device__ __forceinline__ float pair_val(float x10, float x11, float px, float py,
                                          float ce, float c4, float c3n, float c2) {
    float d0 = x10 - px, d1 = x11 - py;
    float s = fmaf(d1, d1, d0 * d0);
    // poly = c4*s^2 - c3*s + c2 ; c3n = -c3
    float poly = fmaf(s, fmaf(s, c4, c3n), c2);
    return __expf(ce * s) * poly;
}

__global__ __launch_bounds__(256) void poisson_lxlx_kernel(
    const float* __restrict__ X1, const float* __restrict__ X2,
    const float* __restrict__ ls, float* __restrict__ out)
{
    const int i  = blockIdx.y;                               // row (X1 point)
    const int j8 = blockIdx.x * blockDim.x + threadIdx.x;    // group of 8 cols
    const int j  = j8 * 8;
    if (j >= N2) return;

    const float l  = ls[0];
    const float a  = 1.0f / (l * l);
    const float a2 = a * a;
    const float c4  = a2 * a2;        //  a^4
    const float c3n = -8.0f * a2 * a; // -8 a^3
    const float c2  = 8.0f * a2;      //  8 a^2
    const float ce  = -0.5f * a;

    const float x10 = X1[2 * i];
    const float x11 = X1[2 * i + 1];

    // 8 consecutive X2 points = 16 contiguous floats = 4 vector loads
    const v4f* p = reinterpret_cast<const v4f*>(X2 + 2 * (size_t)j);
    v4f p0 = p[0], p1 = p[1], p2 = p[2], p3 = p[3];

    v4f r0, r1;
    r0.x = pair_val(x10, x11, p0.x, p0.y, ce, c4, c3n, c2);
    r0.y = pair_val(x10, x11, p0.z, p0.w, ce, c4, c3n, c2);
    r0.z = pair_val(x10, x11, p1.x, p1.y, ce, c4, c3n, c2);
    r0.w = pair_val(x10, x11, p1.z, p1.w, ce, c4, c3n, c2);
    r1.x = pair_val(x10, x11, p2.x, p2.y, ce, c4, c3n, c2);
    r1.y = pair_val(x10, x11, p2.z, p2.w, ce, c4, c3n, c2);
    r1.z = pair_val(x10, x11, p3.x, p3.y, ce, c4, c3n, c2);
    r1.w = pair_val(x10, x11, p3.z, p3.w, ce, c4, c3n, c2);

    v4f* dst = reinterpret_cast<v4f*>(out + (size_t)i * N2 + j);
    __builtin_nontemporal_store(r0, dst);
    __builtin_nontemporal_store(r1, dst + 1);
}

extern "C" void kernel_launch(void* const* d_in, const int* in_sizes, int n_in,
                              void* d_out, int out_size, void* d_ws, size_t ws_size,
                              hipStream_t stream) {
    const float* X1 = (const float*)d_in[0];
    const float* X2 = (const float*)d_in[1];
    const float* ls = (const float*)d_in[2];
    float* out = (float*)d_out;

    dim3 block(256);
    dim3 grid((N2 / 8 + 255) / 256, N1);  // (2, 4096)
    poisson_lxlx_kernel<<<grid, block, 0, stream>>>(X1, X2, ls, out);
}

// Round 3
// 16.792 us; speedup vs baseline: 1.5293x; 1.5293x over previous
//
#include <hip/hip_runtime.h>

// L_x1 L_x2 of RBF kernel k(x1,x2)=exp(-||x1-x2||^2/(2 l^2)) in D=2.
// Closed form: with a = 1/l^2, s = ||x1-x2||^2:
//   L_x1 L_x2 k = exp(-0.5*a*s) * (a^4 s^2 - 8 a^3 s + 8 a^2)

#define N1 4096
#define N2 4096
#define ROWS_PER_BLOCK 4
#define GROUPS 4  // float4 output groups per thread per row (4*256*4 = 4096 cols)

typedef float v4f __attribute__((ext_vector_type(4)));

__device__ __forceinline__ float pair_val(float x10, float x11, float px, float py,
                                          float ce, float c4, float c3n, float c2) {
    float d0 = x10 - px, d1 = x11 - py;
    float s = fmaf(d1, d1, d0 * d0);
    float poly = fmaf(s, fmaf(s, c4, c3n), c2);  // c4*s^2 + c3n*s + c2
    return __expf(ce * s) * poly;
}

__global__ __launch_bounds__(256) void poisson_lxlx_kernel(
    const float* __restrict__ X1, const float* __restrict__ X2,
    const float* __restrict__ ls, float* __restrict__ out)
{
    const int t  = threadIdx.x;
    const int i0 = blockIdx.x * ROWS_PER_BLOCK;

    const float l  = ls[0];
    const float a  = 1.0f / (l * l);
    const float a2 = a * a;
    const float c4  = a2 * a2;
    const float c3n = -8.0f * a2 * a;
    const float c2  = 8.0f * a2;
    const float ce  = -0.5f * a;

    // Cache this thread's X2 points in registers: GROUPS groups of 4 points.
    v4f xa[GROUPS], xb[GROUPS];
#pragma unroll
    for (int g = 0; g < GROUPS; ++g) {
        const int col4 = g * 256 + t;                 // float4-group index in row
        const float* p = X2 + (size_t)col4 * 8;       // 4 points = 8 floats
        xa[g] = *reinterpret_cast<const v4f*>(p);
        xb[g] = *reinterpret_cast<const v4f*>(p + 4);
    }

#pragma unroll
    for (int r = 0; r < ROWS_PER_BLOCK; ++r) {
        const int i = i0 + r;
        const float x10 = X1[2 * i];
        const float x11 = X1[2 * i + 1];
        float* rowp = out + (size_t)i * N2;
#pragma unroll
        for (int g = 0; g < GROUPS; ++g) {
            v4f res;
            res.x = pair_val(x10, x11, xa[g].x, xa[g].y, ce, c4, c3n, c2);
            res.y = pair_val(x10, x11, xa[g].z, xa[g].w, ce, c4, c3n, c2);
            res.z = pair_val(x10, x11, xb[g].x, xb[g].y, ce, c4, c3n, c2);
            res.w = pair_val(x10, x11, xb[g].z, xb[g].w, ce, c4, c3n, c2);
            const int col4 = g * 256 + t;
            *reinterpret_cast<v4f*>(rowp + (size_t)col4 * 4) = res;
        }
    }
}

extern "C" void kernel_launch(void* const* d_in, const int* in_sizes, int n_in,
                              void* d_out, int out_size, void* d_ws, size_t ws_size,
                              hipStream_t stream) {
    const float* X1 = (const float*)d_in[0];
    const float* X2 = (const float*)d_in[1];
    const float* ls = (const float*)d_in[2];
    float* out = (float*)d_out;

    dim3 block(256);
    dim3 grid(N1 / ROWS_PER_BLOCK);  // 1024 blocks
    poisson_lxlx_kernel<<<grid, block, 0, stream>>>(X1, X2, ls, out);
}